// Round 17
// baseline (80.898 us; speedup 1.0000x reference)
//
#include <hip/hip_runtime.h>
#include <hip/hip_bf16.h>

#define NB 8
#define SEQ 2048
#define HD 1024
#define DK 64

// exp2-domain constants: Q pre-scaled by 0.125/ln2, fixed softmax base 8/ln2
#define QSCALE 0.1803368801111244f
#define FIXMAX2 11.541560327111708f

typedef __attribute__((ext_vector_type(4))) float f32x4;
typedef __attribute__((ext_vector_type(8))) short bf16x8;
typedef __attribute__((ext_vector_type(4))) unsigned short u16x4;

// raw barrier: LDS-only fence (lgkmcnt), NO vmcnt drain -> global loads stay in flight
#define LDS_BARRIER() asm volatile("s_waitcnt lgkmcnt(0)\n\ts_barrier" ::: "memory")

__device__ __forceinline__ short f2bf(float f) {
    union { float f; unsigned u; } v; v.f = f;
    unsigned r = v.u + 0x7fffu + ((v.u >> 16) & 1u);
    return (short)(r >> 16);
}
__device__ __forceinline__ float fexp2(float x) {
#if __has_builtin(__builtin_amdgcn_exp2f)
    return __builtin_amdgcn_exp2f(x);
#else
    return exp2f(x);
#endif
}
__device__ __forceinline__ short bf16lo(float f) {
    unsigned r;
    asm("v_cvt_pk_bf16_f32 %0, %1, %1" : "=v"(r) : "v"(f));
    return (short)r;
}
__device__ __forceinline__ bf16x8 pack8(f32x4 v0, f32x4 v1) {
    union { bf16x8 v; __hip_bfloat162 h[4]; } u;
    u.h[0] = __float22bfloat162_rn(make_float2(v0[0], v0[1]));
    u.h[1] = __float22bfloat162_rn(make_float2(v0[2], v0[3]));
    u.h[2] = __float22bfloat162_rn(make_float2(v1[0], v1[1]));
    u.h[3] = __float22bfloat162_rn(make_float2(v1[2], v1[3]));
    return u.v;
}

// ---------------- prep: W pack (blocks 0..767) + lengths (768..775) ----------------
__global__ void prep_kernel(const unsigned* __restrict__ mask,
                            const float* __restrict__ Wq, const float* __restrict__ Wk,
                            const float* __restrict__ Wv,
                            int* __restrict__ lengths, short* __restrict__ Wp) {
    if (blockIdx.x < 768) {
        int idx = blockIdx.x * 256 + threadIdx.x;     // 0..196607
        int j = idx & 7, lane = (idx >> 3) & 63;
        int slot = idx >> 9;                          // 0..383
        int fr = slot % 3, q2 = slot / 3;
        int kh = q2 & 1, cg = (q2 >> 1) & 3, kbg = q2 >> 3;
        int g = lane >> 4, c = lane & 15;
        int n = cg * 3 + fr;
        int m = n >> 2, colm = (n & 3) * 16 + c;
        int k = kbg * 64 + kh * 32 + g * 8 + j;
        const float* W = (m == 0) ? Wq : (m == 1) ? Wk : Wv;
        Wp[idx] = f2bf(W[(size_t)k * DK + colm]);
        return;
    }
    __shared__ int sdet;
    __shared__ int scnt;
    int b = blockIdx.x - 768, t = threadIdx.x;
    if (t == 0) { sdet = 0; scnt = 0; }
    __syncthreads();
    int det = 0;
    for (int i = t; i < 4096; i += 256) {
        unsigned w = mask[i];
        if (w > 1u && w != 0x3F800000u) det = 1;
    }
    if (det) atomicOr(&sdet, 1);
    __syncthreads();
    int cnt = 0;
    if (sdet) {
        const unsigned char* m8 = (const unsigned char*)mask;
        for (int s = t; s < SEQ; s += 256) cnt += (m8[b * SEQ + s] == 0) ? 1 : 0;
    } else {
        for (int s = t; s < SEQ; s += 256) cnt += (mask[b * SEQ + s] == 0u) ? 1 : 0;
    }
    atomicAdd(&scnt, cnt);
    __syncthreads();
    if (t == 0) lengths[b] = scnt;
}

// ---------------- QKV v11: bf16-in-LDS dbuf GEMM, counted-vmcnt pipeline -----------
__global__ __launch_bounds__(256) void qkv_kernel(
    const float* __restrict__ x,
    const float* __restrict__ bq, const float* __restrict__ bk, const float* __restrict__ bv,
    const short* __restrict__ Wp,
    short* __restrict__ Q, short* __restrict__ K, short* __restrict__ Vt) {
    __shared__ short xs[2][32][64];    // 8 KiB bf16, granule-swizzled
    int t = threadIdx.x;
    int cg = t >> 6, lane = t & 63;
    int g = lane >> 4, c = lane & 15;
    int r0 = blockIdx.x * 32;
    int bb = r0 >> 11, sbase = r0 & (SEQ - 1);

    int srow = t >> 3, ch = t & 7;
    const float* xsrc = x + (size_t)(r0 + srow) * HD + ch * 8;
    short* wbase = &xs[0][0][0];
    int wo = srow * 64 + ((ch ^ (srow & 7)) << 3);    // shorts

    const short* wpw = Wp + (size_t)cg * 3072 + (size_t)lane * 8;

    f32x4 z = {0.f, 0.f, 0.f, 0.f};
    f32x4 acc[2][3];
    #pragma unroll
    for (int rf = 0; rf < 2; rf++)
        #pragma unroll
        for (int fr = 0; fr < 3; fr++) acc[rf][fr] = z;

    {
        f32x4 x0 = *(const f32x4*)xsrc;
        f32x4 x1 = *(const f32x4*)(xsrc + 4);
        *(bf16x8*)(wbase + wo) = pack8(x0, x1);
    }
    bf16x8 Bc[2][3];
    #pragma unroll
    for (int kh = 0; kh < 2; kh++)
        #pragma unroll
        for (int fr = 0; fr < 3; fr++)
            Bc[kh][fr] = *(const bf16x8*)(wpw + kh * 1536 + fr * 512);
    f32x4 nxA0 = *(const f32x4*)(xsrc + 64);
    f32x4 nxA1 = *(const f32x4*)(xsrc + 68);
    LDS_BARRIER();

    const short* rbase0 = &xs[0][0][0] + c * 64;
    #pragma unroll
    for (int kbg = 0; kbg < 16; kbg++) {
        int cur = kbg & 1;
        f32x4 nxB0, nxB1;
        bf16x8 Bn[2][3];
        if (kbg < 14) {
            const float* p = xsrc + (kbg + 2) * 64;
            nxB0 = *(const f32x4*)p;
            nxB1 = *(const f32x4*)(p + 4);
        }
        if (kbg < 15) {
            #pragma unroll
            for (int kh = 0; kh < 2; kh++)
                #pragma unroll
                for (int fr = 0; fr < 3; fr++)
                    Bn[kh][fr] = *(const bf16x8*)(wpw + (kbg + 1) * 12288 + kh * 1536 + fr * 512);
        }
        bf16x8 Af[2][2];
        #pragma unroll
        for (int rf = 0; rf < 2; rf++)
            #pragma unroll
            for (int kh = 0; kh < 2; kh++)
                Af[rf][kh] = *(const bf16x8*)(rbase0 + cur * 2048 + rf * 1024
                                              + (((kh * 4 + g) ^ (c & 7)) << 3));
        #pragma unroll
        for (int kh = 0; kh < 2; kh++)
            #pragma unroll
            for (int fr = 0; fr < 3; fr++)
                #pragma unroll
                for (int rf = 0; rf < 2; rf++)
                    acc[rf][fr] = __builtin_amdgcn_mfma_f32_16x16x32_bf16(Af[rf][kh], Bc[kh][fr], acc[rf][fr], 0, 0, 0);
        if (kbg < 15) {
            *(bf16x8*)(wbase + (cur ^ 1) * 2048 + wo) = pack8(nxA0, nxA1);
            #pragma unroll
            for (int kh = 0; kh < 2; kh++)
                #pragma unroll
                for (int fr = 0; fr < 3; fr++) Bc[kh][fr] = Bn[kh][fr];
        }
        if (kbg < 14) { nxA0 = nxB0; nxA1 = nxB1; }
        LDS_BARRIER();
    }

    #pragma unroll
    for (int rf = 0; rf < 2; rf++)
        #pragma unroll
        for (int fr = 0; fr < 3; fr++) {
            int n = cg * 3 + fr;
            int m = n >> 2, colm = (n & 3) * 16 + c;
            const float* bias = (m == 0) ? bq : (m == 1) ? bk : bv;
            float bv_ = bias[colm];
            if (m == 2) {
                u16x4 pk;
                #pragma unroll
                for (int j = 0; j < 4; j++) pk[j] = (unsigned short)f2bf(acc[rf][fr][j] + bv_);
                int srw = sbase + rf * 16 + 4 * g;
                *(u16x4*)(Vt + (size_t)bb * DK * SEQ + (size_t)colm * SEQ + srw) = pk;
            } else {
                #pragma unroll
                for (int j = 0; j < 4; j++) {
                    int row = r0 + rf * 16 + 4 * g + j;
                    float s = acc[rf][fr][j] + bv_;
                    if (m == 0) Q[(size_t)row * DK + colm] = f2bf(s * QSCALE);
                    else        K[(size_t)row * DK + colm] = f2bf(s);
                }
            }
        }
}

// ---------------- attention v17: uniform-work partials + combine --------------------
// Work item = (b, qt, 512-key chunk). Item count/batch = 160 via
// off(qt) = 8k(k+1) + (qt&15)(k+1), k = qt>>4. Grid = 1280 uniform blocks, 8 waves,
// wave = (frag f, stripe sq) does <=2 tile-chains. Fixed-max softmax => partials are
// PLAIN SUMS: block writes unnormalized O (f32) + l; combine normalizes.
__global__ __launch_bounds__(512) void attn_part(
    const short* __restrict__ Q, const short* __restrict__ K_, const short* __restrict__ Vt,
    const int* __restrict__ lengths, float* __restrict__ po, float* __restrict__ pl) {
    __shared__ float macc[8][16][66];          // 33.8 KiB
    __shared__ float ll[8][16];
    short* plds = (short*)&macc[0][0][0];      // aliased P region: 8 x [16][70] shorts

    int bid = blockIdx.x;
    int b = bid & 7;                           // XCD-pinned batch
    int idx = bid >> 3;                        // 0..159
    int qt, ch;
    if (idx < 16)      { qt = idx;                 ch = 0; }
    else if (idx < 48) { qt = 16 + (idx - 16) >> 1; ch = (idx - 16) & 1; }
    else if (idx < 96) { qt = 32 + (idx - 48) / 3; ch = (idx - 48) % 3; }
    else               { qt = 48 + ((idx - 96) >> 2); ch = (idx - 96) & 3; }
    if (idx >= 16 && idx < 48) { qt = 16 + ((idx - 16) >> 1); }   // precedence fix
    int len = lengths[b];
    int qbase = qt * 32;
    if (qbase >= len) return;                  // combine writes zeros for these rows
    int kend = min(len, qbase + 32);
    int klo = ch << 9;
    if (klo >= kend) return;                   // chunk never read by combine
    int ntiles = (kend + 63) >> 6;

    int t = threadIdx.x;
    int w = t >> 6, lane = t & 63;
    int g = lane >> 4, c = lane & 15;
    int f = w & 1, sq = w >> 1;

    const short* Qb = Q + ((size_t)b * SEQ + qbase + f * 16) * DK;
    const short* Kb = K_ + (size_t)b * SEQ * DK;
    const short* Vb = Vt + (size_t)b * DK * SEQ;

    bf16x8 qa[2];
    qa[0] = *(const bf16x8*)(Qb + c * DK + g * 8);
    qa[1] = *(const bf16x8*)(Qb + c * DK + 32 + g * 8);

    int rowcap[4];
    #pragma unroll
    for (int j = 0; j < 4; j++)
        rowcap[j] = min(qbase + f * 16 + 4 * g + j, len - 1);

    f32x4 z = {0.f, 0.f, 0.f, 0.f};
    f32x4 acc[4] = {z, z, z, z};
    float l_r[4] = {0.f, 0.f, 0.f, 0.f};

    short* pldsw = plds + w * 1120;            // [16][70] shorts per wave

    #pragma unroll
    for (int ti = 0; ti < 2; ti++) {
        int tg = ch * 8 + sq + ti * 4;
        if (tg >= ntiles) break;
        int kb = tg * 64;
        bf16x8 kh0[2][2], kh1[2][2];
        #pragma unroll
        for (int kt = 0; kt < 2; kt++) {
            const short* kp = Kb + (size_t)(kb + kt * 16 + c) * DK + g * 8;
            kh0[kt][0] = *(const bf16x8*)kp;
            kh0[kt][1] = *(const bf16x8*)(kp + 32);
        }
        #pragma unroll
        for (int kt = 0; kt < 2; kt++) {
            const short* kp = Kb + (size_t)(kb + 32 + kt * 16 + c) * DK + g * 8;
            kh1[kt][0] = *(const bf16x8*)kp;
            kh1[kt][1] = *(const bf16x8*)(kp + 32);
        }
        f32x4 sf[4];
        __builtin_amdgcn_s_setprio(1);
        #pragma unroll
        for (int kt = 0; kt < 2; kt++) {
            f32x4 t0 = __builtin_amdgcn_mfma_f32_16x16x32_bf16(qa[0], kh0[kt][0], z, 0, 0, 0);
            sf[kt] = __builtin_amdgcn_mfma_f32_16x16x32_bf16(qa[1], kh0[kt][1], t0, 0, 0, 0);
        }
        #pragma unroll
        for (int kt = 0; kt < 2; kt++) {
            f32x4 t0 = __builtin_amdgcn_mfma_f32_16x16x32_bf16(qa[0], kh1[kt][0], z, 0, 0, 0);
            sf[kt + 2] = __builtin_amdgcn_mfma_f32_16x16x32_bf16(qa[1], kh1[kt][1], t0, 0, 0, 0);
        }
        __builtin_amdgcn_s_setprio(0);
        #pragma unroll
        for (int kt = 0; kt < 4; kt++) {
            int key = kb + kt * 16 + c;
            #pragma unroll
            for (int j = 0; j < 4; j++) {
                float s = (key > rowcap[j]) ? -1e30f : sf[kt][j];
                float p = fexp2(s - FIXMAX2);
                sf[kt][j] = p;
                l_r[j] += p;
            }
        }
        #pragma unroll
        for (int kt = 0; kt < 4; kt++)
            #pragma unroll
            for (int j = 0; j < 4; j++)
                pldsw[(4 * g + j) * 70 + kt * 16 + c] = bf16lo(sf[kt][j]);
        bf16x8 pa0 = *(const bf16x8*)(pldsw + c * 70 + g * 8);
        bf16x8 pa1 = *(const bf16x8*)(pldsw + c * 70 + 32 + g * 8);
        #pragma unroll
        for (int n = 0; n < 4; n++) {
            const short* vp = Vb + (size_t)(n * 16 + c) * SEQ + kb + g * 8;
            bf16x8 v0 = *(const bf16x8*)vp;
            bf16x8 v1 = *(const bf16x8*)(vp + 32);
            __builtin_amdgcn_s_setprio(1);
            acc[n] = __builtin_amdgcn_mfma_f32_16x16x32_bf16(pa0, v0, acc[n], 0, 0, 0);
            acc[n] = __builtin_amdgcn_mfma_f32_16x16x32_bf16(pa1, v1, acc[n], 0, 0, 0);
            __builtin_amdgcn_s_setprio(0);
        }
    }

    #pragma unroll
    for (int d = 1; d < 16; d <<= 1)
        #pragma unroll
        for (int j = 0; j < 4; j++) l_r[j] += __shfl_xor(l_r[j], d);

    __syncthreads();   // plds lifetime over -> reuse as macc
    #pragma unroll
    for (int n = 0; n < 4; n++)
        #pragma unroll
        for (int j = 0; j < 4; j++)
            macc[w][4 * g + j][n * 16 + c] = acc[n][j];
    if (c == 0) {
        #pragma unroll
        for (int j = 0; j < 4; j++)
            ll[w][4 * g + j] = l_r[j];
    }
    __syncthreads();
    // merge 4 stripe-waves per frag -> unnormalized partial (plain sums)
    {
        int row = t >> 4, seg = t & 15;
        int ff = row >> 4, r16 = row & 15;
        float o[4] = {0.f, 0.f, 0.f, 0.f};
        #pragma unroll
        for (int s2 = 0; s2 < 4; s2++) {
            int wv = ff + 2 * s2;
            #pragma unroll
            for (int i = 0; i < 4; i++) o[i] += macc[wv][r16][seg * 4 + i];
        }
        *(f32x4*)(po + (size_t)bid * 2048 + row * 64 + seg * 4) = *(f32x4*)o;
        if (seg == 0)
            pl[bid * 32 + row] = ll[ff][r16] + ll[ff + 2][r16] + ll[ff + 4][r16] + ll[ff + 6][r16];
    }
}

// ---------------- combine: sum chunk partials, normalize, write (zeros if padded) --
__global__ __launch_bounds__(256) void attn_combine(
    const float* __restrict__ po, const float* __restrict__ pl,
    const int* __restrict__ lengths, float* __restrict__ out) {
    int blk = blockIdx.x;              // 512 = 8 batches x 64 q-tiles
    int b = blk & 7, qt = blk >> 3;
    int len = lengths[b];
    int qbase = qt * 32;
    int t = threadIdx.x;
    int row = t >> 3, seg = t & 7;     // 8 f32 per thread
    int r = qbase + row;
    float o[8] = {0.f, 0.f, 0.f, 0.f, 0.f, 0.f, 0.f, 0.f};
    if (r < len) {
        int kend = min(len, qbase + 32);
        int nact = (kend + 511) >> 9;
        int k = qt >> 4;
        int off = 8 * k * (k + 1) + (qt & 15) * (k + 1);
        float L = 0.f;
        for (int c2 = 0; c2 < nact; c2++) {
            int pit = (off + c2) * 8 + b;
            L += pl[pit * 32 + row];
            const float* pp = po + (size_t)pit * 2048 + row * 64 + seg * 8;
            #pragma unroll
            for (int i = 0; i < 8; i++) o[i] += pp[i];
        }
        float inv = 1.f / L;
        #pragma unroll
        for (int i = 0; i < 8; i++) o[i] *= inv;
    }
    float* op = out + ((size_t)b * SEQ + r) * DK + seg * 8;
    *(f32x4*)op = *(f32x4*)&o[0];
    *(f32x4*)(op + 4) = *(f32x4*)&o[4];
}

extern "C" void kernel_launch(void* const* d_in, const int* in_sizes, int n_in,
                              void* d_out, int out_size, void* d_ws, size_t ws_size,
                              hipStream_t stream) {
    const float* x  = (const float*)d_in[0];
    const unsigned* mask = (const unsigned*)d_in[1];
    const float* Wq = (const float*)d_in[2];
    const float* bq = (const float*)d_in[3];
    const float* Wk = (const float*)d_in[4];
    const float* bk = (const float*)d_in[5];
    const float* Wv = (const float*)d_in[6];
    const float* bv = (const float*)d_in[7];
    float* out = (float*)d_out;

    char* ws = (char*)d_ws;
    int*   lengths = (int*)ws;                          // 256 B
    short* Wp = (short*)(ws + 256);                     // 384 KiB (Wp2 layout)
    short* Q  = (short*)(ws + 393472);                  // 2 MiB
    short* K  = (short*)(ws + 2490624);                 // 2 MiB
    short* Vt = (short*)(ws + 4587776);                 // 2 MiB
    float* po = (float*)(ws + 6684928);                 // 10 MiB (1280 x 32 x 64 f32)
    float* pl = (float*)(ws + 17170688);                // 160 KiB

    hipLaunchKernelGGL(prep_kernel, dim3(776), dim3(256), 0, stream, mask, Wq, Wk, Wv, lengths, Wp);
    hipLaunchKernelGGL(qkv_kernel, dim3(512), dim3(256), 0, stream,
                       x, bq, bk, bv, Wp, Q, K, Vt);
    hipLaunchKernelGGL(attn_part, dim3(1280), dim3(512), 0, stream,
                       Q, K, Vt, lengths, po, pl);
    hipLaunchKernelGGL(attn_combine, dim3(NB * 64), dim3(256), 0, stream,
                       po, pl, lengths, out);
}

// Round 18
// 54.244 us; speedup vs baseline: 1.4914x; 1.4914x over previous
//
#include <hip/hip_runtime.h>
#include <hip/hip_bf16.h>

#define NB 8
#define SEQ 2048
#define HD 1024
#define DK 64

// exp2-domain constants: Q pre-scaled by 0.125/ln2, fixed softmax base 8/ln2
#define QSCALE 0.1803368801111244f
#define FIXMAX2 11.541560327111708f

typedef __attribute__((ext_vector_type(4))) float f32x4;
typedef __attribute__((ext_vector_type(8))) short bf16x8;
typedef __attribute__((ext_vector_type(4))) unsigned short u16x4;

// raw barrier: LDS-only fence (lgkmcnt), NO vmcnt drain -> global loads stay in flight
#define LDS_BARRIER() asm volatile("s_waitcnt lgkmcnt(0)\n\ts_barrier" ::: "memory")
// pin 8 loaded fragments live -> compiler batches the loads and emits ONE vmcnt wait
#define TOUCH8(a,b,c2,d,e,f2,g2,h) \
    asm volatile("" :: "v"(a), "v"(b), "v"(c2), "v"(d), "v"(e), "v"(f2), "v"(g2), "v"(h))

__device__ __forceinline__ short f2bf(float f) {
    union { float f; unsigned u; } v; v.f = f;
    unsigned r = v.u + 0x7fffu + ((v.u >> 16) & 1u);
    return (short)(r >> 16);
}
__device__ __forceinline__ float fexp2(float x) {
#if __has_builtin(__builtin_amdgcn_exp2f)
    return __builtin_amdgcn_exp2f(x);
#else
    return exp2f(x);
#endif
}
__device__ __forceinline__ short bf16lo(float f) {
    unsigned r;
    asm("v_cvt_pk_bf16_f32 %0, %1, %1" : "=v"(r) : "v"(f));
    return (short)r;
}
__device__ __forceinline__ bf16x8 pack8(f32x4 v0, f32x4 v1) {
    union { bf16x8 v; __hip_bfloat162 h[4]; } u;
    u.h[0] = __float22bfloat162_rn(make_float2(v0[0], v0[1]));
    u.h[1] = __float22bfloat162_rn(make_float2(v0[2], v0[3]));
    u.h[2] = __float22bfloat162_rn(make_float2(v1[0], v1[1]));
    u.h[3] = __float22bfloat162_rn(make_float2(v1[2], v1[3]));
    return u.v;
}

// ---------------- prep: W pack (blocks 0..767) + lengths (768..775) ----------------
__global__ void prep_kernel(const unsigned* __restrict__ mask,
                            const float* __restrict__ Wq, const float* __restrict__ Wk,
                            const float* __restrict__ Wv,
                            int* __restrict__ lengths, short* __restrict__ Wp) {
    if (blockIdx.x < 768) {
        int idx = blockIdx.x * 256 + threadIdx.x;     // 0..196607
        int j = idx & 7, lane = (idx >> 3) & 63;
        int slot = idx >> 9;                          // 0..383
        int fr = slot % 3, q2 = slot / 3;
        int kh = q2 & 1, cg = (q2 >> 1) & 3, kbg = q2 >> 3;
        int g = lane >> 4, c = lane & 15;
        int n = cg * 3 + fr;
        int m = n >> 2, colm = (n & 3) * 16 + c;
        int k = kbg * 64 + kh * 32 + g * 8 + j;
        const float* W = (m == 0) ? Wq : (m == 1) ? Wk : Wv;
        Wp[idx] = f2bf(W[(size_t)k * DK + colm]);
        return;
    }
    __shared__ int sdet;
    __shared__ int scnt;
    int b = blockIdx.x - 768, t = threadIdx.x;
    if (t == 0) { sdet = 0; scnt = 0; }
    __syncthreads();
    int det = 0;
    for (int i = t; i < 4096; i += 256) {
        unsigned w = mask[i];
        if (w > 1u && w != 0x3F800000u) det = 1;
    }
    if (det) atomicOr(&sdet, 1);
    __syncthreads();
    int cnt = 0;
    if (sdet) {
        const unsigned char* m8 = (const unsigned char*)mask;
        for (int s = t; s < SEQ; s += 256) cnt += (m8[b * SEQ + s] == 0) ? 1 : 0;
    } else {
        for (int s = t; s < SEQ; s += 256) cnt += (mask[b * SEQ + s] == 0u) ? 1 : 0;
    }
    atomicAdd(&scnt, cnt);
    __syncthreads();
    if (t == 0) lengths[b] = scnt;
}

// ---------------- QKV v11: bf16-in-LDS dbuf GEMM, counted-vmcnt pipeline -----------
__global__ __launch_bounds__(256) void qkv_kernel(
    const float* __restrict__ x,
    const float* __restrict__ bq, const float* __restrict__ bk, const float* __restrict__ bv,
    const short* __restrict__ Wp,
    short* __restrict__ Q, short* __restrict__ K, short* __restrict__ Vt) {
    __shared__ short xs[2][32][64];    // 8 KiB bf16, granule-swizzled
    int t = threadIdx.x;
    int cg = t >> 6, lane = t & 63;
    int g = lane >> 4, c = lane & 15;
    int r0 = blockIdx.x * 32;
    int bb = r0 >> 11, sbase = r0 & (SEQ - 1);

    int srow = t >> 3, ch = t & 7;
    const float* xsrc = x + (size_t)(r0 + srow) * HD + ch * 8;
    short* wbase = &xs[0][0][0];
    int wo = srow * 64 + ((ch ^ (srow & 7)) << 3);    // shorts

    const short* wpw = Wp + (size_t)cg * 3072 + (size_t)lane * 8;

    f32x4 z = {0.f, 0.f, 0.f, 0.f};
    f32x4 acc[2][3];
    #pragma unroll
    for (int rf = 0; rf < 2; rf++)
        #pragma unroll
        for (int fr = 0; fr < 3; fr++) acc[rf][fr] = z;

    {
        f32x4 x0 = *(const f32x4*)xsrc;
        f32x4 x1 = *(const f32x4*)(xsrc + 4);
        *(bf16x8*)(wbase + wo) = pack8(x0, x1);
    }
    bf16x8 Bc[2][3];
    #pragma unroll
    for (int kh = 0; kh < 2; kh++)
        #pragma unroll
        for (int fr = 0; fr < 3; fr++)
            Bc[kh][fr] = *(const bf16x8*)(wpw + kh * 1536 + fr * 512);
    f32x4 nxA0 = *(const f32x4*)(xsrc + 64);
    f32x4 nxA1 = *(const f32x4*)(xsrc + 68);
    LDS_BARRIER();

    const short* rbase0 = &xs[0][0][0] + c * 64;
    #pragma unroll
    for (int kbg = 0; kbg < 16; kbg++) {
        int cur = kbg & 1;
        f32x4 nxB0, nxB1;
        bf16x8 Bn[2][3];
        if (kbg < 14) {
            const float* p = xsrc + (kbg + 2) * 64;
            nxB0 = *(const f32x4*)p;
            nxB1 = *(const f32x4*)(p + 4);
        }
        if (kbg < 15) {
            #pragma unroll
            for (int kh = 0; kh < 2; kh++)
                #pragma unroll
                for (int fr = 0; fr < 3; fr++)
                    Bn[kh][fr] = *(const bf16x8*)(wpw + (kbg + 1) * 12288 + kh * 1536 + fr * 512);
        }
        bf16x8 Af[2][2];
        #pragma unroll
        for (int rf = 0; rf < 2; rf++)
            #pragma unroll
            for (int kh = 0; kh < 2; kh++)
                Af[rf][kh] = *(const bf16x8*)(rbase0 + cur * 2048 + rf * 1024
                                              + (((kh * 4 + g) ^ (c & 7)) << 3));
        #pragma unroll
        for (int kh = 0; kh < 2; kh++)
            #pragma unroll
            for (int fr = 0; fr < 3; fr++)
                #pragma unroll
                for (int rf = 0; rf < 2; rf++)
                    acc[rf][fr] = __builtin_amdgcn_mfma_f32_16x16x32_bf16(Af[rf][kh], Bc[kh][fr], acc[rf][fr], 0, 0, 0);
        if (kbg < 15) {
            *(bf16x8*)(wbase + (cur ^ 1) * 2048 + wo) = pack8(nxA0, nxA1);
            #pragma unroll
            for (int kh = 0; kh < 2; kh++)
                #pragma unroll
                for (int fr = 0; fr < 3; fr++) Bc[kh][fr] = Bn[kh][fr];
        }
        if (kbg < 14) { nxA0 = nxB0; nxA1 = nxB1; }
        LDS_BARRIER();
    }

    #pragma unroll
    for (int rf = 0; rf < 2; rf++)
        #pragma unroll
        for (int fr = 0; fr < 3; fr++) {
            int n = cg * 3 + fr;
            int m = n >> 2, colm = (n & 3) * 16 + c;
            const float* bias = (m == 0) ? bq : (m == 1) ? bk : bv;
            float bv_ = bias[colm];
            if (m == 2) {
                u16x4 pk;
                #pragma unroll
                for (int j = 0; j < 4; j++) pk[j] = (unsigned short)f2bf(acc[rf][fr][j] + bv_);
                int srw = sbase + rf * 16 + 4 * g;
                *(u16x4*)(Vt + (size_t)bb * DK * SEQ + (size_t)colm * SEQ + srw) = pk;
            } else {
                #pragma unroll
                for (int j = 0; j < 4; j++) {
                    int row = r0 + rf * 16 + 4 * g + j;
                    float s = acc[rf][fr][j] + bv_;
                    if (m == 0) Q[(size_t)row * DK + colm] = f2bf(s * QSCALE);
                    else        K[(size_t)row * DK + colm] = f2bf(s);
                }
            }
        }
}

// ---------------- flash attention v18: v15 structure + batched-load pinning --------
// Diagnosis (R16/R17): compiler min-registers to 48 VGPR -> 16 loads/tile serialize
// at ~500cyc each. Fix: asm-touch all 8 K (and 8 V) fragments after issue, then
// sched_barrier(0) -> loads batch-issue with ONE vmcnt wait; V latency hides under
// the exp/P-pack phase. Forces ~110 VGPR (structural liveness, rule #17).
__global__ __launch_bounds__(512) void attn_kernel(
    const short* __restrict__ Q, const short* __restrict__ K_, const short* __restrict__ Vt,
    const int* __restrict__ lengths, float* __restrict__ out) {
    __shared__ float macc[8][32][66];          // merge buffer (67.6 KiB)
    __shared__ float ll[8][32];
    short* plds = (short*)&macc[0][0][0];      // aliased P-transpose region (35.8 KiB)

    int bid = blockIdx.x;
    int b = bid & 7;                           // XCD-pinned batch
    int qt = 63 - (bid >> 3);                  // heavy tiles dispatch first
    int len = lengths[b];
    int qbase = qt * 32;
    int t = threadIdx.x;
    int w = t >> 6, lane = t & 63;
    int g = lane >> 4, c = lane & 15;

    if (qbase >= len) {                        // fully padded tile -> zeros
        int row = t >> 4, col0 = (t & 15) * 4;
        f32x4 zz = {0.f, 0.f, 0.f, 0.f};
        *(f32x4*)(out + ((size_t)b * SEQ + qbase + row) * DK + col0) = zz;
        return;
    }

    int kend = min(len, qbase + 32);
    int ntiles = (kend + 63) >> 6;
    const short* Qb = Q + ((size_t)b * SEQ + qbase) * DK;
    const short* Kb = K_ + (size_t)b * SEQ * DK;
    const short* Vb = Vt + (size_t)b * DK * SEQ;

    bf16x8 qa[2][2];
    #pragma unroll
    for (int f = 0; f < 2; f++)
        #pragma unroll
        for (int kh = 0; kh < 2; kh++)
            qa[f][kh] = *(const bf16x8*)(Qb + (f * 16 + c) * DK + kh * 32 + g * 8);

    int rowcap[2][4];
    #pragma unroll
    for (int f = 0; f < 2; f++)
        #pragma unroll
        for (int j = 0; j < 4; j++)
            rowcap[f][j] = min(qbase + f * 16 + 4 * g + j, len - 1);

    f32x4 z = {0.f, 0.f, 0.f, 0.f};
    f32x4 acc[2][4];
    float l_r[2][4];
    #pragma unroll
    for (int f = 0; f < 2; f++) {
        #pragma unroll
        for (int n = 0; n < 4; n++) acc[f][n] = z;
        #pragma unroll
        for (int j = 0; j < 4; j++) l_r[f][j] = 0.f;
    }

    short* pldsw = plds + w * 2240;            // [2][16][70] shorts per wave

    for (int tt = w; tt < ntiles; tt += 8) {
        int kb = tt * 64;
        // issue ALL 8 K loads, pin them live, fence -> batch issue + single wait
        bf16x8 kh0[2][2], kh1[2][2];
        #pragma unroll
        for (int kt = 0; kt < 2; kt++) {
            const short* kp = Kb + (size_t)(kb + kt * 16 + c) * DK + g * 8;
            kh0[kt][0] = *(const bf16x8*)kp;
            kh0[kt][1] = *(const bf16x8*)(kp + 32);
        }
        #pragma unroll
        for (int kt = 0; kt < 2; kt++) {
            const short* kp = Kb + (size_t)(kb + 32 + kt * 16 + c) * DK + g * 8;
            kh1[kt][0] = *(const bf16x8*)kp;
            kh1[kt][1] = *(const bf16x8*)(kp + 32);
        }
        TOUCH8(kh0[0][0], kh0[0][1], kh0[1][0], kh0[1][1],
               kh1[0][0], kh1[0][1], kh1[1][0], kh1[1][1]);
        __builtin_amdgcn_sched_barrier(0);
        // QK^T
        f32x4 sf[2][4];
        __builtin_amdgcn_s_setprio(1);
        #pragma unroll
        for (int kt = 0; kt < 2; kt++)
            #pragma unroll
            for (int f = 0; f < 2; f++) {
                f32x4 t0 = __builtin_amdgcn_mfma_f32_16x16x32_bf16(qa[f][0], kh0[kt][0], z, 0, 0, 0);
                sf[f][kt] = __builtin_amdgcn_mfma_f32_16x16x32_bf16(qa[f][1], kh0[kt][1], t0, 0, 0, 0);
            }
        #pragma unroll
        for (int kt = 0; kt < 2; kt++)
            #pragma unroll
            for (int f = 0; f < 2; f++) {
                f32x4 t0 = __builtin_amdgcn_mfma_f32_16x16x32_bf16(qa[f][0], kh1[kt][0], z, 0, 0, 0);
                sf[f][kt + 2] = __builtin_amdgcn_mfma_f32_16x16x32_bf16(qa[f][1], kh1[kt][1], t0, 0, 0, 0);
            }
        __builtin_amdgcn_s_setprio(0);
        // issue ALL 8 V loads now -> latency hides under exp + P pack
        bf16x8 vr[4][2];
        #pragma unroll
        for (int n = 0; n < 4; n++) {
            const short* vp = Vb + (size_t)(n * 16 + c) * SEQ + kb + g * 8;
            vr[n][0] = *(const bf16x8*)vp;
            vr[n][1] = *(const bf16x8*)(vp + 32);
        }
        // mask + exp2 + per-lane l accumulation
        #pragma unroll
        for (int kt = 0; kt < 4; kt++) {
            int key = kb + kt * 16 + c;
            #pragma unroll
            for (int f = 0; f < 2; f++)
                #pragma unroll
                for (int j = 0; j < 4; j++) {
                    float s = (key > rowcap[f][j]) ? -1e30f : sf[f][kt][j];
                    float p = fexp2(s - FIXMAX2);
                    sf[f][kt][j] = p;
                    l_r[f][j] += p;
                }
        }
        // P: D-layout -> LDS -> A-layout (wave-private lockstep, no barrier)
        #pragma unroll
        for (int f = 0; f < 2; f++)
            #pragma unroll
            for (int kt = 0; kt < 4; kt++)
                #pragma unroll
                for (int j = 0; j < 4; j++)
                    pldsw[f * 1120 + (4 * g + j) * 70 + kt * 16 + c] = bf16lo(sf[f][kt][j]);
        bf16x8 pa[2][2];
        #pragma unroll
        for (int f = 0; f < 2; f++) {
            pa[f][0] = *(const bf16x8*)(pldsw + f * 1120 + c * 70 + g * 8);
            pa[f][1] = *(const bf16x8*)(pldsw + f * 1120 + c * 70 + 32 + g * 8);
        }
        TOUCH8(vr[0][0], vr[0][1], vr[1][0], vr[1][1],
               vr[2][0], vr[2][1], vr[3][0], vr[3][1]);
        __builtin_amdgcn_sched_barrier(0);
        // PV
        __builtin_amdgcn_s_setprio(1);
        #pragma unroll
        for (int n = 0; n < 4; n++)
            #pragma unroll
            for (int f = 0; f < 2; f++) {
                acc[f][n] = __builtin_amdgcn_mfma_f32_16x16x32_bf16(pa[f][0], vr[n][0], acc[f][n], 0, 0, 0);
                acc[f][n] = __builtin_amdgcn_mfma_f32_16x16x32_bf16(pa[f][1], vr[n][1], acc[f][n], 0, 0, 0);
            }
        __builtin_amdgcn_s_setprio(0);
    }

    // one-time l reduction across the 16 lanes holding each row
    #pragma unroll
    for (int d = 1; d < 16; d <<= 1)
        #pragma unroll
        for (int f = 0; f < 2; f++)
            #pragma unroll
            for (int j = 0; j < 4; j++) l_r[f][j] += __shfl_xor(l_r[f][j], d);

    __syncthreads();   // plds lifetime over -> reuse as macc
    #pragma unroll
    for (int f = 0; f < 2; f++)
        #pragma unroll
        for (int n = 0; n < 4; n++)
            #pragma unroll
            for (int j = 0; j < 4; j++)
                macc[w][f * 16 + 4 * g + j][n * 16 + c] = acc[f][n][j];
    if (c == 0) {
        #pragma unroll
        for (int f = 0; f < 2; f++)
            #pragma unroll
            for (int j = 0; j < 4; j++)
                ll[w][f * 16 + 4 * g + j] = l_r[f][j];
    }
    __syncthreads();
    // merge: plain sums (all waves share the same fixed max)
    {
        int row = t >> 4, seg = t & 15;
        int r = qbase + row;
        float* op = out + ((size_t)b * SEQ + r) * DK + seg * 4;
        float o[4] = {0.f, 0.f, 0.f, 0.f};
        if (r < len) {
            float L = 0.f;
            #pragma unroll
            for (int wv = 0; wv < 8; wv++) L += ll[wv][row];
            #pragma unroll
            for (int wv = 0; wv < 8; wv++)
                #pragma unroll
                for (int i = 0; i < 4; i++) o[i] += macc[wv][row][seg * 4 + i];
            float inv = 1.f / L;
            #pragma unroll
            for (int i = 0; i < 4; i++) o[i] *= inv;
        }
        #pragma unroll
        for (int i = 0; i < 4; i++) op[i] = o[i];
    }
}

extern "C" void kernel_launch(void* const* d_in, const int* in_sizes, int n_in,
                              void* d_out, int out_size, void* d_ws, size_t ws_size,
                              hipStream_t stream) {
    const float* x  = (const float*)d_in[0];
    const unsigned* mask = (const unsigned*)d_in[1];
    const float* Wq = (const float*)d_in[2];
    const float* bq = (const float*)d_in[3];
    const float* Wk = (const float*)d_in[4];
    const float* bk = (const float*)d_in[5];
    const float* Wv = (const float*)d_in[6];
    const float* bv = (const float*)d_in[7];
    float* out = (float*)d_out;

    char* ws = (char*)d_ws;
    int*   lengths = (int*)ws;                          // 256 B
    short* Wp = (short*)(ws + 256);                     // 384 KiB (Wp2 layout)
    short* Q  = (short*)(ws + 393472);                  // 2 MiB
    short* K  = (short*)(ws + 2490624);                 // 2 MiB
    short* Vt = (short*)(ws + 4587776);                 // 2 MiB

    hipLaunchKernelGGL(prep_kernel, dim3(776), dim3(256), 0, stream, mask, Wq, Wk, Wv, lengths, Wp);
    hipLaunchKernelGGL(qkv_kernel, dim3(512), dim3(256), 0, stream,
                       x, bq, bk, bv, Wp, Q, K, Vt);
    hipLaunchKernelGGL(attn_kernel, dim3(NB * 64), dim3(512), 0, stream,
                       Q, K, Vt, lengths, out);
}